// Round 9
// baseline (225.013 us; speedup 1.0000x reference)
//
#include <hip/hip_runtime.h>
#include <math.h>

// GEBLNet via Gram-matrix reduction (R9: w-half pair split to break the
// 128-VGPR occupancy cliff).
//   T[u] = sum_{v,w} w2[u,v,w] * tr(We2[v] @ We2[w]) -> 169 unique Gram values,
//   w2 folded per-launch into CTt[169][12] float4 (setup kernel).
// Layer 1 exact. Phase-2 thread = (p, u, k, h): h=0 owns w 0..6, h=1 owns
// w 7..12 (+ a zero-padded 13th slot so the unroll is uniform). Partial B and
// partial H are linear in the w-split, so each half runs the whole v-loop and
// the pair merges its 6 H floats with __shfl_xor(.,1) (pairs wave-aligned).
// Halves the loop-invariant Wcol preload 78->42 regs -> natural VGPR < 128
// -> 4 waves/SIMD instead of 2 (m69: occupancy halves at vgpr=64/128/256).
// LESSON (R4+R7): launch_bounds min-waves arg overshoots to 64 VGPR + spills.
// LESSON (R6): never reinterpret-cast local arrays (alloca -> scratch).
// LESSON (R8): compiler re-hoists LDS invariants; cut them at the algorithm.

#define NPTS 8192
#define NP 3
#define THRESH 0.001f

__global__ void geblnet_setup(const float* __restrict__ w2,
                              float4* __restrict__ CTt) {
    int j = blockIdx.x * blockDim.x + threadIdx.x;
    if (j >= 12 * 169) return;
    int u = j / 169, it = j % 169;
    const float* W = w2 + u * 25 * 25 * 2;
#define WR(v, w) W[((v) * 25 + (w)) * 2]
#define WI(v, w) W[((v) * 25 + (w)) * 2 + 1]
    float c0, c1, c2, c3;
    if (it < 78) {                       // S pairs, a<=b
        int q = it, a = 0;
        while (q >= 12 - a) { q -= 12 - a; ++a; }
        int b = a + q;
        float ar = WR(a, b) + (a != b ? WR(b, a) : 0.f);
        float ai = WI(a, b) + (a != b ? WI(b, a) : 0.f);
        float br = WR(12 + a, 12 + b) + (a != b ? WR(12 + b, 12 + a) : 0.f);
        float bi = WI(12 + a, 12 + b) + (a != b ? WI(12 + b, 12 + a) : 0.f);
        c0 = ar + br; c1 = bi - ai; c2 = ai + bi; c3 = ar - br;
    } else if (it < 156) {               // Hm pairs, a<=b
        int q = it - 78, a = 0;
        while (q >= 12 - a) { q -= 12 - a; ++a; }
        int b = a + q;
        if (a != b) {
            float gr = WR(a, 12 + b) + WR(12 + b, a);
            float gi = WI(a, 12 + b) + WI(12 + b, a);
            float dr = WR(b, 12 + a) + WR(12 + a, b);
            float di = WI(b, 12 + a) + WI(12 + a, b);
            c0 = gr + dr; c1 = di - gi; c2 = gi + di; c3 = gr - dr;
        } else {
            float er = WR(a, 12 + a) + WR(12 + a, a);
            float ei = WI(a, 12 + a) + WI(12 + a, a);
            c0 = er; c1 = 0.f; c2 = ei; c3 = 0.f;
        }
    } else if (it < 168) {               // trace terms
        int a = it - 156;
        float fr = WR(a, 24) + WR(24, a), fi = WI(a, 24) + WI(24, a);
        float pr = WR(12 + a, 24) + WR(24, 12 + a);
        float pi = WI(12 + a, 24) + WI(24, 12 + a);
        c0 = fr + pr; c1 = pi - fi; c2 = fi + pi; c3 = fr - pr;
    } else {                             // unit-unit
        c0 = 3.f * WR(24, 24); c1 = 0.f; c2 = 3.f * WI(24, 24); c3 = 0.f;
    }
    CTt[it * 12 + u] = make_float4(c0, c1, c2, c3);
#undef WR
#undef WI
}

__global__ __launch_bounds__(256) void geblnet_main(
    const float2* __restrict__ x2,      // (8192, 10, 9) complex
    const float2* __restrict__ w1g,     // (12,13,13) complex
    const float* __restrict__ dw,       // (24,)
    const float* __restrict__ db,       // (1,)
    const float4* __restrict__ CTt,     // (169,12)
    float* __restrict__ out)            // (8192,)
{
    // Overlay region: phases 1-2 = Wrow (p-stride 170, row-stride 10, v<12);
    //                 phases 4-5 = GV[p*170+it]. Disjoint lifetimes.
    __shared__ float2 WeGV[NP * 170];                    // 4080 B
    // k-major: Wcol[(p*3+k)*44 + w*3 + j] = We[w][j][k]; w=12 identity at
    // 36..38; slots 39..41 ZERO (pad target for h=1's 7th unroll slot).
    __shared__ float2 Wcol[NP * 3 * 44];                 // 3168 B
    __shared__ float2 Hs[NP][108];                       // 2592 B
    __shared__ float2 Tpar[NP][84];                      // 2016 B
    __shared__ float2 tr1[NP][12];                       //  288 B
    __shared__ float  sc1[NP][12];                       //  144 B

    const int t = threadIdx.x;
    const int pbase = blockIdx.x * NP;

    // ---- phase 1: build We1 in row-major (v<12) and k-major (v<=12) layouts
    for (int j = t; j < NP * 117; j += 256) {
        int p = j / 117, rr = j - p * 117;
        if (pbase + p >= NPTS) continue;
        int v = rr / 9, ik = rr - v * 9;
        int i = ik / 3, jj = ik - i * 3;
        if (v < 12) {
            const float2* xp = x2 + (size_t)(pbase + p) * 90;
            float2 val;
            if (v < 6) val = xp[(4 + v) * 9 + ik];
            else { float2 s = xp[(v - 2) * 9 + jj * 3 + i]; val = make_float2(s.x, -s.y); }
            WeGV[p * 170 + v * 10 + ik] = val;              // row-major
            Wcol[(p * 3 + jj) * 44 + v * 3 + i] = val;      // k-major (k=jj)
        } else {
            Wcol[(p * 3 + jj) * 44 + 36 + i] =
                make_float2((i == jj) ? 1.f : 0.f, 0.f);    // identity channel
            Wcol[(p * 3 + jj) * 44 + 39 + i] =
                make_float2(0.f, 0.f);                      // zero pad (w=13)
        }
    }
    __syncthreads();

    // ---- phase 2: layer 1, thread=(p,u,k,h), 216 active
    if (t < NP * 72) {
        int p = t / 72, rr = t - p * 72;
        int u = rr / 6, kk = rr - u * 6, k = kk >> 1, h = kk & 1;
        if (pbase + p < NPTS) {
            const float2* wcb = &Wcol[(p * 3 + k) * 44 + h * 21];  // w = 7h + m
            // half preload: 21 float2 (42 VGPR), fully unrolled const indices
            float2 wc[7][3];
            #pragma unroll
            for (int m = 0; m < 7; ++m) {
                wc[m][0] = wcb[m * 3 + 0];
                wc[m][1] = wcb[m * 3 + 1];
                wc[m][2] = wcb[m * 3 + 2];
            }
            const float2* wrow = w1g + u * 169;
            const int wlast = h ? 12 : 6;      // clamp for the padded slot
            float h0r = 0.f, h0i = 0.f, h1r = 0.f, h1i = 0.f, h2r = 0.f, h2i = 0.f;

            for (int v = 0; v < 12; ++v) {
                const float2* cp = wrow + v * 13 + h * 7;
                float b0r = 0.f, b0i = 0.f, b1r = 0.f, b1i = 0.f, b2r = 0.f, b2i = 0.f;
                #pragma unroll
                for (int m = 0; m < 7; ++m) {
                    float2 cc = (m == 6) ? wrow[v * 13 + wlast] : cp[m];
                    float2 e0 = wc[m][0], e1 = wc[m][1], e2 = wc[m][2];
                    b0r += cc.x * e0.x - cc.y * e0.y;  b0i += cc.x * e0.y + cc.y * e0.x;
                    b1r += cc.x * e1.x - cc.y * e1.y;  b1i += cc.x * e1.y + cc.y * e1.x;
                    b2r += cc.x * e2.x - cc.y * e2.y;  b2i += cc.x * e2.y + cc.y * e2.x;
                }
                const float2* a = &WeGV[p * 170 + v * 10];
                {
                    float2 a0 = a[0], a1 = a[1], a2 = a[2];
                    h0r += a0.x * b0r - a0.y * b0i + a1.x * b1r - a1.y * b1i + a2.x * b2r - a2.y * b2i;
                    h0i += a0.x * b0i + a0.y * b0r + a1.x * b1i + a1.y * b1r + a2.x * b2i + a2.y * b2r;
                }
                {
                    float2 a0 = a[3], a1 = a[4], a2 = a[5];
                    h1r += a0.x * b0r - a0.y * b0i + a1.x * b1r - a1.y * b1i + a2.x * b2r - a2.y * b2i;
                    h1i += a0.x * b0i + a0.y * b0r + a1.x * b1i + a1.y * b1r + a2.x * b2i + a2.y * b2r;
                }
                {
                    float2 a0 = a[6], a1 = a[7], a2 = a[8];
                    h2r += a0.x * b0r - a0.y * b0i + a1.x * b1r - a1.y * b1i + a2.x * b2r - a2.y * b2i;
                    h2i += a0.x * b0i + a0.y * b0r + a1.x * b1i + a1.y * b1r + a2.x * b2i + a2.y * b2r;
                }
            }
            // v = 12: We[12] = I  ->  H += B(partial)
            {
                const float2* cp = wrow + 12 * 13 + h * 7;
                #pragma unroll
                for (int m = 0; m < 7; ++m) {
                    float2 cc = (m == 6) ? wrow[12 * 13 + wlast] : cp[m];
                    float2 e0 = wc[m][0], e1 = wc[m][1], e2 = wc[m][2];
                    h0r += cc.x * e0.x - cc.y * e0.y;  h0i += cc.x * e0.y + cc.y * e0.x;
                    h1r += cc.x * e1.x - cc.y * e1.y;  h1i += cc.x * e1.y + cc.y * e1.x;
                    h2r += cc.x * e2.x - cc.y * e2.y;  h2i += cc.x * e2.y + cc.y * e2.x;
                }
            }
            // pair merge (h=0 lane t even, h=1 lane t odd, always same wave)
            h0r += __shfl_xor(h0r, 1);  h0i += __shfl_xor(h0i, 1);
            h1r += __shfl_xor(h1r, 1);  h1i += __shfl_xor(h1i, 1);
            h2r += __shfl_xor(h2r, 1);  h2i += __shfl_xor(h2i, 1);
            if (h == 0) {
                Hs[p][u * 9 + 0 + k] = make_float2(h0r, h0i);
                Hs[p][u * 9 + 3 + k] = make_float2(h1r, h1i);
                Hs[p][u * 9 + 6 + k] = make_float2(h2r, h2i);
            }
        }
    }
    __syncthreads();

    // ---- phase 3: traces + gerelu + trnorm scales
    if (t < NP && pbase + t < NPTS) {
        int p = t;
        float m = 0.f; float g[12]; float2 tl[12];
        #pragma unroll
        for (int u = 0; u < 12; ++u) {
            float2 a = Hs[p][u * 9 + 0], b = Hs[p][u * 9 + 4], c = Hs[p][u * 9 + 8];
            float2 tt = make_float2(a.x + b.x + c.x, a.y + b.y + c.y);
            tl[u] = tt;
            float gg = tt.x > 0.f ? tt.x : 0.f;
            g[u] = gg;
            m += gg * sqrtf(tt.x * tt.x + tt.y * tt.y);
        }
        float inv = 1.f / fmaxf(m * (1.f / 12.f), THRESH);
        #pragma unroll
        for (int u = 0; u < 12; ++u) { sc1[p][u] = g[u] * inv; tr1[p][u] = tl[u]; }
    }
    __syncthreads();

    // ---- phase 4: Gram values -> GV (overlays Wrow; dead since phase 2)
    for (int j = t; j < NP * 169; j += 256) {
        int p = j / 169, it = j - p * 169;
        if (pbase + p >= NPTS) continue;
        float2 val;
        if (it < 156) {
            int q = it < 78 ? it : it - 78;
            float fs = sqrtf(625.0f - 8.0f * (float)q);   // exact at bucket edges
            int a = (int)((25.0f - fs) * 0.5f);
            int b = q - (a * (25 - a)) / 2 + a;
            const float2* Ha = &Hs[p][a * 9];
            const float2* Hb = &Hs[p][b * 9];
            float s = sc1[p][a] * sc1[p][b];
            float vr = 0.f, vi = 0.f;
            if (it < 78) {                    // S = tr(Aa Ab)
                #pragma unroll
                for (int i = 0; i < 3; ++i)
                    #pragma unroll
                    for (int jj = 0; jj < 3; ++jj) {
                        float2 A = Ha[i * 3 + jj], B = Hb[jj * 3 + i];
                        vr += A.x * B.x - A.y * B.y;
                        vi += A.x * B.y + A.y * B.x;
                    }
            } else {                          // Hm = tr(Aa Ab^H)
                #pragma unroll
                for (int e = 0; e < 9; ++e) {
                    float2 A = Ha[e], B = Hb[e];
                    vr += A.x * B.x + A.y * B.y;
                    vi += A.y * B.x - A.x * B.y;
                }
            }
            val = make_float2(s * vr, s * vi);
        } else if (it < 168) {
            int a = it - 156;
            float s = sc1[p][a]; float2 tt = tr1[p][a];
            val = make_float2(s * tt.x, s * tt.y);
        } else {
            val = make_float2(1.f, 0.f);
        }
        WeGV[p * 170 + it] = val;
    }
    __syncthreads();

    // ---- phase 5: coefficient contraction, thread=(q,p,u); 7 chunks of <=25
    if (t < 252) {
        int q = t / 36, r = t - q * 36, p = r / 12, u = r - p * 12;
        if (pbase + p < NPTS) {
            int i0 = q * 25, i1 = (q == 6) ? 169 : i0 + 25;
            float tre = 0.f, tim = 0.f;
            for (int it = i0; it < i1; ++it) {
                float4 c = CTt[it * 12 + u];
                float2 gv = WeGV[p * 170 + it];
                tre += c.x * gv.x + c.y * gv.y;
                tim += c.z * gv.x + c.w * gv.y;
            }
            Tpar[p][u * 7 + q] = make_float2(tre, tim);
        }
    }
    __syncthreads();

    // ---- phase 6: layer-2 gerelu + trnorm + dense head
    if (t < NP && pbase + t < NPTS) {
        int p = t;
        float m = 0.f; float2 T[12]; float gg[12];
        #pragma unroll
        for (int u = 0; u < 12; ++u) {
            float2 tt = make_float2(0.f, 0.f);
            #pragma unroll
            for (int q = 0; q < 7; ++q) {
                float2 A = Tpar[p][u * 7 + q];
                tt.x += A.x; tt.y += A.y;
            }
            T[u] = tt;
            float g = tt.x > 0.f ? tt.x : 0.f;
            gg[u] = g;
            m += g * sqrtf(tt.x * tt.x + tt.y * tt.y);
        }
        float inv = 1.f / fmaxf(m * (1.f / 12.f), THRESH);
        float acc = db[0];
        #pragma unroll
        for (int u = 0; u < 12; ++u) {
            float s = gg[u] * inv * (1.f / 3.f);
            acc += s * (T[u].x * dw[2 * u] + T[u].y * dw[2 * u + 1]);
        }
        out[pbase + p] = acc;
    }
}

extern "C" void kernel_launch(void* const* d_in, const int* in_sizes, int n_in,
                              void* d_out, int out_size, void* d_ws, size_t ws_size,
                              hipStream_t stream) {
    const float* x  = (const float*)d_in[0];
    const float* w1 = (const float*)d_in[1];
    const float* w2 = (const float*)d_in[2];
    const float* dw = (const float*)d_in[3];
    const float* db = (const float*)d_in[4];
    float* outp = (float*)d_out;
    float4* CTt = (float4*)d_ws;          // 12*169*16 B = 32448 B

    geblnet_setup<<<(12 * 169 + 255) / 256, 256, 0, stream>>>(w2, CTt);

    const int nblocks = (NPTS + NP - 1) / NP;   // 2731
    geblnet_main<<<nblocks, 256, 0, stream>>>(
        (const float2*)x, (const float2*)w1, dw, db, CTt, outp);
}

// Round 10
// 145.091 us; speedup vs baseline: 1.5508x; 1.5508x over previous
//
#include <hip/hip_runtime.h>
#include <math.h>

// GEBLNet via Gram-matrix reduction (R10: one WAVE per point).
//   T[u] = sum_{v,w} w2[u,v,w] * tr(We2[v] @ We2[w]) -> 169 unique Gram values,
//   w2 folded per-launch into CTt[169][12] float4 (setup kernel).
// Execution shape: 8192 blocks x 64 threads (1 wave = 1 point). All barriers
// are single-wave no-ops -> no phase coupling; resident waves hedge each
// other's latency. Register diet to get under the 128-VGPR occupancy cliff:
//   - phase-2 w-range processed in two sequential halves (#pragma unroll 1):
//     only 21 float2 of Wcol live at once (R5's 78-reg full preload -> 140).
//   - #pragma unroll 1 on the v-loop: one w1 row-half in flight (R9 evidence:
//     unrolled v-loop software-pipelines global loads into ~50 regs).
// LESSON (R4+R7): launch_bounds min-waves arg overshoots to 64 VGPR + spills.
// LESSON (R6): never reinterpret-cast local arrays (alloca -> scratch).
// LESSON (R8/R9): compiler hoists LDS invariants AND pipelines global loads;
// cut register demand at the algorithm level, not with allocator caps.

#define NPTS 8192
#define THRESH 0.001f

__global__ void geblnet_setup(const float* __restrict__ w2,
                              float4* __restrict__ CTt) {
    int j = blockIdx.x * blockDim.x + threadIdx.x;
    if (j >= 12 * 169) return;
    int u = j / 169, it = j % 169;
    const float* W = w2 + u * 25 * 25 * 2;
#define WR(v, w) W[((v) * 25 + (w)) * 2]
#define WI(v, w) W[((v) * 25 + (w)) * 2 + 1]
    float c0, c1, c2, c3;
    if (it < 78) {                       // S pairs, a<=b
        int q = it, a = 0;
        while (q >= 12 - a) { q -= 12 - a; ++a; }
        int b = a + q;
        float ar = WR(a, b) + (a != b ? WR(b, a) : 0.f);
        float ai = WI(a, b) + (a != b ? WI(b, a) : 0.f);
        float br = WR(12 + a, 12 + b) + (a != b ? WR(12 + b, 12 + a) : 0.f);
        float bi = WI(12 + a, 12 + b) + (a != b ? WI(12 + b, 12 + a) : 0.f);
        c0 = ar + br; c1 = bi - ai; c2 = ai + bi; c3 = ar - br;
    } else if (it < 156) {               // Hm pairs, a<=b
        int q = it - 78, a = 0;
        while (q >= 12 - a) { q -= 12 - a; ++a; }
        int b = a + q;
        if (a != b) {
            float gr = WR(a, 12 + b) + WR(12 + b, a);
            float gi = WI(a, 12 + b) + WI(12 + b, a);
            float dr = WR(b, 12 + a) + WR(12 + a, b);
            float di = WI(b, 12 + a) + WI(12 + a, b);
            c0 = gr + dr; c1 = di - gi; c2 = gi + di; c3 = gr - dr;
        } else {
            float er = WR(a, 12 + a) + WR(12 + a, a);
            float ei = WI(a, 12 + a) + WI(12 + a, a);
            c0 = er; c1 = 0.f; c2 = ei; c3 = 0.f;
        }
    } else if (it < 168) {               // trace terms
        int a = it - 156;
        float fr = WR(a, 24) + WR(24, a), fi = WI(a, 24) + WI(24, a);
        float pr = WR(12 + a, 24) + WR(24, 12 + a);
        float pi = WI(12 + a, 24) + WI(24, 12 + a);
        c0 = fr + pr; c1 = pi - fi; c2 = fi + pi; c3 = fr - pr;
    } else {                             // unit-unit
        c0 = 3.f * WR(24, 24); c1 = 0.f; c2 = 3.f * WI(24, 24); c3 = 0.f;
    }
    CTt[it * 12 + u] = make_float4(c0, c1, c2, c3);
#undef WR
#undef WI
}

__global__ __launch_bounds__(64) void geblnet_main(
    const float2* __restrict__ x2,      // (8192, 10, 9) complex
    const float2* __restrict__ w1g,     // (12,13,13) complex
    const float* __restrict__ dw,       // (24,)
    const float* __restrict__ db,       // (1,)
    const float4* __restrict__ CTt,     // (169,12)
    float* __restrict__ out)            // (8192,)
{
    // Overlay: phases 1-2 = We row-major (stride 10); phases 4-5 = GV[169].
    __shared__ float2 WeGV[170];        // 1360 B
    // k-major: Wcol[k*44 + w*3 + j] = We[w][j][k]; w=12 identity at 36..38;
    // slots 39..41 ZERO (pad for h=1's 7th unroll slot).
    __shared__ float2 Wcol[3 * 44];     // 1056 B
    __shared__ float2 Hs[108];          //  864 B
    __shared__ float2 Tpar[60];         //  480 B
    __shared__ float2 tr1[12];          //   96 B
    __shared__ float  sc1[12];          //   48 B
    __shared__ float  gb[12];           //   48 B
    __shared__ float  tra[12];          //   48 B

    const int t = threadIdx.x;
    const int p = blockIdx.x;

    // ---- phase 1: build We1 in row-major (v<12) and k-major layouts
    for (int j = t; j < 117; j += 64) {
        int v = j / 9, ik = j - v * 9;
        int i = ik / 3, jj = ik - i * 3;
        if (v < 12) {
            const float2* xp = x2 + (size_t)p * 90;
            float2 val;
            if (v < 6) val = xp[(4 + v) * 9 + ik];
            else { float2 s = xp[(v - 2) * 9 + jj * 3 + i]; val = make_float2(s.x, -s.y); }
            WeGV[v * 10 + ik] = val;                // row-major
            Wcol[jj * 44 + v * 3 + i] = val;        // k-major (k=jj)
        } else {
            Wcol[jj * 44 + 36 + i] = make_float2((i == jj) ? 1.f : 0.f, 0.f);
            Wcol[jj * 44 + 39 + i] = make_float2(0.f, 0.f);   // zero pad
        }
    }
    __syncthreads();

    // ---- phase 2: layer 1, lane=(u,k), sequential w-halves
    if (t < 36) {
        int u = t / 3, k = t - u * 3;
        const float2* wrow = w1g + u * 169;
        float h0r = 0.f, h0i = 0.f, h1r = 0.f, h1i = 0.f, h2r = 0.f, h2i = 0.f;

        #pragma unroll 1
        for (int h = 0; h < 2; ++h) {
            const float2* wcb = &Wcol[k * 44 + h * 21];   // w = 7h + m
            float2 wc[7][3];
            #pragma unroll
            for (int m = 0; m < 7; ++m) {
                wc[m][0] = wcb[m * 3 + 0];
                wc[m][1] = wcb[m * 3 + 1];
                wc[m][2] = wcb[m * 3 + 2];
            }
            const int wlast = h ? 12 : 6;   // clamp for the padded slot

            #pragma unroll 1
            for (int v = 0; v < 13; ++v) {
                const float2* cp = wrow + v * 13 + h * 7;
                float b0r = 0.f, b0i = 0.f, b1r = 0.f, b1i = 0.f, b2r = 0.f, b2i = 0.f;
                #pragma unroll
                for (int m = 0; m < 7; ++m) {
                    float2 cc = (m == 6) ? wrow[v * 13 + wlast] : cp[m];
                    float2 e0 = wc[m][0], e1 = wc[m][1], e2 = wc[m][2];
                    b0r += cc.x * e0.x - cc.y * e0.y;  b0i += cc.x * e0.y + cc.y * e0.x;
                    b1r += cc.x * e1.x - cc.y * e1.y;  b1i += cc.x * e1.y + cc.y * e1.x;
                    b2r += cc.x * e2.x - cc.y * e2.y;  b2i += cc.x * e2.y + cc.y * e2.x;
                }
                if (v < 12) {
                    const float2* a = &WeGV[v * 10];
                    {
                        float2 a0 = a[0], a1 = a[1], a2 = a[2];
                        h0r += a0.x * b0r - a0.y * b0i + a1.x * b1r - a1.y * b1i + a2.x * b2r - a2.y * b2i;
                        h0i += a0.x * b0i + a0.y * b0r + a1.x * b1i + a1.y * b1r + a2.x * b2i + a2.y * b2r;
                    }
                    {
                        float2 a0 = a[3], a1 = a[4], a2 = a[5];
                        h1r += a0.x * b0r - a0.y * b0i + a1.x * b1r - a1.y * b1i + a2.x * b2r - a2.y * b2i;
                        h1i += a0.x * b0i + a0.y * b0r + a1.x * b1i + a1.y * b1r + a2.x * b2i + a2.y * b2r;
                    }
                    {
                        float2 a0 = a[6], a1 = a[7], a2 = a[8];
                        h2r += a0.x * b0r - a0.y * b0i + a1.x * b1r - a1.y * b1i + a2.x * b2r - a2.y * b2i;
                        h2i += a0.x * b0i + a0.y * b0r + a1.x * b1i + a1.y * b1r + a2.x * b2i + a2.y * b2r;
                    }
                } else {                  // We[12] = I  ->  H += B(partial)
                    h0r += b0r; h0i += b0i;
                    h1r += b1r; h1i += b1i;
                    h2r += b2r; h2i += b2i;
                }
            }
        }
        Hs[u * 9 + 0 + k] = make_float2(h0r, h0i);
        Hs[u * 9 + 3 + k] = make_float2(h1r, h1i);
        Hs[u * 9 + 6 + k] = make_float2(h2r, h2i);
    }
    __syncthreads();

    // ---- phase 3: traces + gerelu + trnorm scales
    if (t < 12) {
        float2 a = Hs[t * 9 + 0], b = Hs[t * 9 + 4], c = Hs[t * 9 + 8];
        float2 tt = make_float2(a.x + b.x + c.x, a.y + b.y + c.y);
        tr1[t] = tt;
        float gg = tt.x > 0.f ? tt.x : 0.f;
        gb[t] = gg;
        tra[t] = gg * sqrtf(tt.x * tt.x + tt.y * tt.y);
    }
    __syncthreads();
    if (t < 12) {
        float m = 0.f;
        #pragma unroll
        for (int u = 0; u < 12; ++u) m += tra[u];
        sc1[t] = gb[t] / fmaxf(m * (1.f / 12.f), THRESH);
    }
    __syncthreads();

    // ---- phase 4: Gram values -> GV (overlays We row-major; dead now)
    for (int it = t; it < 169; it += 64) {
        float2 val;
        if (it < 156) {
            int q = it < 78 ? it : it - 78;
            float fs = sqrtf(625.0f - 8.0f * (float)q);   // exact at bucket edges
            int a = (int)((25.0f - fs) * 0.5f);
            int b = q - (a * (25 - a)) / 2 + a;
            const float2* Ha = &Hs[a * 9];
            const float2* Hb = &Hs[b * 9];
            float s = sc1[a] * sc1[b];
            float vr = 0.f, vi = 0.f;
            if (it < 78) {                    // S = tr(Aa Ab)
                #pragma unroll
                for (int i = 0; i < 3; ++i)
                    #pragma unroll
                    for (int jj = 0; jj < 3; ++jj) {
                        float2 A = Ha[i * 3 + jj], B = Hb[jj * 3 + i];
                        vr += A.x * B.x - A.y * B.y;
                        vi += A.x * B.y + A.y * B.x;
                    }
            } else {                          // Hm = tr(Aa Ab^H)
                #pragma unroll
                for (int e = 0; e < 9; ++e) {
                    float2 A = Ha[e], B = Hb[e];
                    vr += A.x * B.x + A.y * B.y;
                    vi += A.y * B.x - A.x * B.y;
                }
            }
            val = make_float2(s * vr, s * vi);
        } else if (it < 168) {
            int a = it - 156;
            float s = sc1[a]; float2 tt = tr1[a];
            val = make_float2(s * tt.x, s * tt.y);
        } else {
            val = make_float2(1.f, 0.f);
        }
        WeGV[it] = val;
    }
    __syncthreads();

    // ---- phase 5: coefficient contraction, lane=(q,u), 60 active
    if (t < 60) {
        int q = t / 12, u = t - q * 12;
        int i0 = q * 34, i1 = (q == 4) ? 169 : i0 + 34;
        float tre = 0.f, tim = 0.f;
        for (int it = i0; it < i1; ++it) {
            float4 c = CTt[it * 12 + u];
            float2 gv = WeGV[it];
            tre += c.x * gv.x + c.y * gv.y;
            tim += c.z * gv.x + c.w * gv.y;
        }
        Tpar[u * 5 + q] = make_float2(tre, tim);
    }
    __syncthreads();

    // ---- phase 6: layer-2 gerelu + trnorm + dense head
    if (t < 12) {
        float2 tt = make_float2(0.f, 0.f);
        #pragma unroll
        for (int q = 0; q < 5; ++q) {
            float2 A = Tpar[t * 5 + q];
            tt.x += A.x; tt.y += A.y;
        }
        tr1[t] = tt;
        float g = tt.x > 0.f ? tt.x : 0.f;
        gb[t] = g;
        tra[t] = g * sqrtf(tt.x * tt.x + tt.y * tt.y);
    }
    __syncthreads();
    if (t == 0) {
        float m = 0.f;
        #pragma unroll
        for (int u = 0; u < 12; ++u) m += tra[u];
        float inv = 1.f / fmaxf(m * (1.f / 12.f), THRESH);
        float acc = db[0];
        #pragma unroll
        for (int u = 0; u < 12; ++u) {
            float s = gb[u] * inv * (1.f / 3.f);
            acc += s * (tr1[u].x * dw[2 * u] + tr1[u].y * dw[2 * u + 1]);
        }
        out[p] = acc;
    }
}

extern "C" void kernel_launch(void* const* d_in, const int* in_sizes, int n_in,
                              void* d_out, int out_size, void* d_ws, size_t ws_size,
                              hipStream_t stream) {
    const float* x  = (const float*)d_in[0];
    const float* w1 = (const float*)d_in[1];
    const float* w2 = (const float*)d_in[2];
    const float* dw = (const float*)d_in[3];
    const float* db = (const float*)d_in[4];
    float* outp = (float*)d_out;
    float4* CTt = (float4*)d_ws;          // 12*169*16 B = 32448 B

    geblnet_setup<<<(12 * 169 + 255) / 256, 256, 0, stream>>>(w2, CTt);

    geblnet_main<<<NPTS, 64, 0, stream>>>(
        (const float2*)x, (const float2*)w1, dw, db, CTt, outp);
}